// Round 1
// baseline (189.083 us; speedup 1.0000x reference)
//
#include <hip/hip_runtime.h>
#include <hip/hip_bf16.h>

// z = x[B,D] . W[O,D]^T + bias[O]; out = z*z.  B=131072, D=128, O=256. fp32 I/O.
// Strategy: bf16 MFMA (16x16x32), W staged fp32->bf16 in LDS once per block,
// x rows loaded global->reg per wave. Memory-bound target ~32us.

#define B_ROWS 131072
#define D_DIM  128
#define O_DIM  256
#define ROWS_PER_BLOCK 128   // 8 waves x 16 rows
#define THREADS 512
#define W_PITCH 136          // 128 + 8 bf16 pad: row stride = 68 dwords -> 2-way bank alias (free)

using bf16x8 = __attribute__((ext_vector_type(8))) short;  // 8 bf16 bit-patterns (4 VGPRs)
using f32x4  = __attribute__((ext_vector_type(4))) float;

__device__ __forceinline__ short bf16bits(float f) {
    __hip_bfloat16 h = __float2bfloat16(f);
    return __builtin_bit_cast(short, h);
}

__global__ __launch_bounds__(THREADS, 4)
void hyper_linear_sq_kernel(const float* __restrict__ x,
                            const float* __restrict__ weight,
                            const float* __restrict__ bias,
                            float* __restrict__ out) {
    __shared__ short Wlds[O_DIM * W_PITCH];   // 256*136*2 = 69632 B

    const int tid = threadIdx.x;

    // ---- Stage W: fp32 global -> bf16 LDS (coalesced float4 reads) ----
    {
        const float4* wv = (const float4*)weight;   // 8192 float4 total
        #pragma unroll
        for (int it = 0; it < 16; ++it) {
            int idx = it * THREADS + tid;           // float4 index
            float4 v = wv[idx];
            int e   = idx << 2;                     // element index
            int row = e >> 7;                       // / 128
            int c   = e & 127;
            short4 p;
            p.x = bf16bits(v.x); p.y = bf16bits(v.y);
            p.z = bf16bits(v.z); p.w = bf16bits(v.w);
            *(short4*)&Wlds[row * W_PITCH + c] = p; // 8B aligned (136%8==0... 136*2=272, c*2 mult of 8)
        }
    }

    const int lane = tid & 63;
    const int wid  = tid >> 6;     // wave 0..7
    const int n16  = lane & 15;    // A row-in-tile / B col-in-tile / C col
    const int quad = lane >> 4;    // k-chunk selector; C row quad

    const long rowbase = (long)blockIdx.x * ROWS_PER_BLOCK + wid * 16;

    // ---- A fragments: x[rowbase+n16][ks*32 + quad*8 .. +8], fp32->bf16 ----
    const float* xr = x + (rowbase + n16) * D_DIM + quad * 8;
    bf16x8 a[4];
    #pragma unroll
    for (int ks = 0; ks < 4; ++ks) {
        float4 h0 = *(const float4*)(xr + ks * 32);
        float4 h1 = *(const float4*)(xr + ks * 32 + 4);
        bf16x8 t;
        t[0] = bf16bits(h0.x); t[1] = bf16bits(h0.y);
        t[2] = bf16bits(h0.z); t[3] = bf16bits(h0.w);
        t[4] = bf16bits(h1.x); t[5] = bf16bits(h1.y);
        t[6] = bf16bits(h1.z); t[7] = bf16bits(h1.w);
        a[ks] = t;
    }

    f32x4 acc[16];
    #pragma unroll
    for (int ct = 0; ct < 16; ++ct) acc[ct] = (f32x4){0.f, 0.f, 0.f, 0.f};

    __syncthreads();

    // ---- K-loop: 4 ksteps x 16 col-tiles, B frag = W[col = ct*16+n16][k] ----
    #pragma unroll
    for (int ks = 0; ks < 4; ++ks) {
        #pragma unroll
        for (int ct = 0; ct < 16; ++ct) {
            bf16x8 b = *(const bf16x8*)&Wlds[(ct * 16 + n16) * W_PITCH + ks * 32 + quad * 8];
            acc[ct] = __builtin_amdgcn_mfma_f32_16x16x32_bf16(a[ks], b, acc[ct], 0, 0, 0);
        }
    }

    // ---- Epilogue: C[row = quad*4+r][col = ct*16+n16]; z=acc+bias; out=z*z ----
    #pragma unroll
    for (int ct = 0; ct < 16; ++ct) {
        int col = ct * 16 + n16;
        float bv = bias[col];
        #pragma unroll
        for (int r = 0; r < 4; ++r) {
            long row = rowbase + quad * 4 + r;
            float z = acc[ct][r] + bv;
            out[row * O_DIM + col] = z * z;
        }
    }
}

extern "C" void kernel_launch(void* const* d_in, const int* in_sizes, int n_in,
                              void* d_out, int out_size, void* d_ws, size_t ws_size,
                              hipStream_t stream) {
    const float* x    = (const float*)d_in[0];
    const float* w    = (const float*)d_in[1];
    const float* bias = (const float*)d_in[2];
    float* out        = (float*)d_out;
    dim3 grid(B_ROWS / ROWS_PER_BLOCK);   // 1024
    hipLaunchKernelGGL(hyper_linear_sq_kernel, grid, dim3(THREADS), 0, stream,
                       x, w, bias, out);
}